// Round 1
// baseline (6589.323 us; speedup 1.0000x reference)
//
#include <hip/hip_runtime.h>
#include <math.h>

#define TPB 256

// ---------------------------------------------------------------------------
// CG init: computes the 9 real-basis Clebsch-Gordan tensors on device each
// launch (ws is re-poisoned before every timed call). Mirrors the reference's
// _cg_complex / _u_real / _cg_real exactly, in double precision.
// Path table: (l1,l2,l3), dense size (2l1+1)(2l2+1)(2l3+1), offset in ws:
//  p0 (0,0,0)  1   @0      p1 (0,1,1)  9  @1      p2 (0,2,2) 25 @10
//  p3 (1,0,1)  9   @35     p4 (1,1,0)  9  @44     p5 (1,1,1) 27 @53
//  p6 (1,1,2) 45   @80     p7 (1,2,1) 45  @125    p8 (1,2,2) 75 @170   total 245
// ---------------------------------------------------------------------------

__device__ double dfact(int n){ double r = 1.0; for (int i = 2; i <= n; ++i) r *= (double)i; return r; }

__device__ void build_u(int l, double ur[5][5], double ui[5][5]){
  for (int i = 0; i < 5; ++i) for (int j = 0; j < 5; ++j){ ur[i][j] = 0.0; ui[i][j] = 0.0; }
  ur[l][l] = 1.0;
  double s = 1.0 / sqrt(2.0);
  for (int m = 1; m <= l; ++m){
    double sg = (m & 1) ? -1.0 : 1.0;
    ur[l + m][l + m] = sg * s;   // (-1)^m / sqrt2
    ur[l + m][l - m] = s;        // 1/sqrt2
    ui[l - m][l - m] = s;        // i/sqrt2
    ui[l - m][l + m] = -sg * s;  // -i(-1)^m/sqrt2
  }
}

__global__ void cg_init_kernel(float* __restrict__ cg){
  int p = threadIdx.x;
  if (p >= 9) return;
  const int L1[9] = {0,0,0,1,1,1,1,1,1};
  const int L2[9] = {0,1,2,0,1,1,1,2,2};
  const int L3[9] = {0,1,2,1,0,1,2,1,2};
  const int OFF[9] = {0,1,10,35,44,53,80,125,170};
  int l1 = L1[p], l2 = L2[p], l3 = L3[p];
  int n1 = 2*l1+1, n2 = 2*l2+1, n3 = 2*l3+1;

  double Cc[5][5][5];
  for (int i = 0; i < 5; ++i) for (int j = 0; j < 5; ++j) for (int k = 0; k < 5; ++k) Cc[i][j][k] = 0.0;
  for (int m1 = -l1; m1 <= l1; ++m1) for (int m2 = -l2; m2 <= l2; ++m2){
    int m3 = m1 + m2;
    if (m3 < -l3 || m3 > l3) continue;
    double pref = sqrt((double)(2*l3+1) * dfact(l1+l2-l3) * dfact(l1-l2+l3) * dfact(-l1+l2+l3) / dfact(l1+l2+l3+1));
    pref *= sqrt(dfact(l3+m3)*dfact(l3-m3)*dfact(l1-m1)*dfact(l1+m1)*dfact(l2-m2)*dfact(l2+m2));
    double s = 0.0;
    for (int k = 0; k <= l1 + l2 - l3; ++k){
      int a0 = k, a1 = l1+l2-l3-k, a2 = l1-m1-k, a3 = l2+m2-k, a4 = l3-l2+m1+k, a5 = l3-l1-m2+k;
      if (a0 < 0 || a1 < 0 || a2 < 0 || a3 < 0 || a4 < 0 || a5 < 0) continue;
      double d = dfact(a0)*dfact(a1)*dfact(a2)*dfact(a3)*dfact(a4)*dfact(a5);
      s += ((k & 1) ? -1.0 : 1.0) / d;
    }
    Cc[m1+l1][m2+l2][m3+l3] = pref * s;
  }

  double U1r[5][5], U1i[5][5], U2r[5][5], U2i[5][5], U3r[5][5], U3i[5][5];
  build_u(l1, U1r, U1i); build_u(l2, U2r, U2i); build_u(l3, U3r, U3i);

  double Tre[5][5][5], Tim[5][5][5];
  double mre = 0.0, mim = 0.0;
  for (int a = 0; a < n1; ++a) for (int b = 0; b < n2; ++b) for (int c = 0; c < n3; ++c){
    double sr = 0.0, si = 0.0;
    for (int m = 0; m < n1; ++m) for (int n = 0; n < n2; ++n) for (int o = 0; o < n3; ++o){
      double cc = Cc[m][n][o];
      if (cc == 0.0) continue;
      double xre = U1r[a][m], xim = U1i[a][m];
      double yre = U2r[b][n], yim = U2i[b][n];
      double zr = xre*yre - xim*yim, zi = xre*yim + xim*yre;
      double wr = U3r[c][o], wi = -U3i[c][o];          // conj(U3)
      double pr = zr*wr - zi*wi, pi = zr*wi + zi*wr;
      sr += pr * cc; si += pi * cc;
    }
    Tre[a][b][c] = sr; Tim[a][b][c] = si;
    if (fabs(sr) > mre) mre = fabs(sr);
    if (fabs(si) > mim) mim = fabs(si);
  }
  int use_re = (mre >= mim);
  for (int a = 0; a < n1; ++a) for (int b = 0; b < n2; ++b) for (int c = 0; c < n3; ++c)
    cg[OFF[p] + (a*n2 + b)*n3 + c] = (float)(use_re ? Tre[a][b][c] : Tim[a][b][c]);
}

// ---------------------------------------------------------------------------
// Fused per-edge kernel: MLP (16->64->64 fused, then 64->288 inside u-loop),
// spherical harmonics, Y-contracted CG (B_p), tensor product, atomic scatter.
// All weight/CG loads are wave-uniform -> scalar pipe; VALU does pure FMA.
// ---------------------------------------------------------------------------

__device__ __forceinline__ float silu_f(float x){
  float t = __expf(-x);
  return x * __builtin_amdgcn_rcpf(1.0f + t);   // x * sigmoid(x); inf-safe
}

__global__ void tfn_edge_kernel(
    const float* __restrict__ nf, const float* __restrict__ ef,
    const float* __restrict__ ev, const int* __restrict__ ei,
    const float* __restrict__ W0, const float* __restrict__ W1,
    const float* __restrict__ W2, const float* __restrict__ cg,
    float* __restrict__ out, int E)
{
  int e = blockIdx.x * TPB + threadIdx.x;
  if (e >= E) return;

  // ---- edge features ----
  float f0[16];
  #pragma unroll
  for (int q = 0; q < 16; ++q) f0[q] = ef[(size_t)e*16 + q];

  // ---- MLP layers 0+1 fused (h0 streamed, never materialized) ----
  float h1[64];
  #pragma unroll
  for (int j = 0; j < 64; ++j) h1[j] = 0.f;
  for (int k = 0; k < 64; ++k){            // dynamic k: all weight idx uniform
    float a = 0.f;
    #pragma unroll
    for (int q = 0; q < 16; ++q) a += f0[q] * W0[q*64 + k];
    float g = silu_f(a);
    #pragma unroll
    for (int j = 0; j < 64; ++j) h1[j] += g * W1[k*64 + j];
  }
  #pragma unroll
  for (int j = 0; j < 64; ++j) h1[j] = silu_f(h1[j]);

  // ---- spherical harmonics of normalized edge vector ----
  float ex = ev[(size_t)e*3+0], eyv = ev[(size_t)e*3+1], ezv = ev[(size_t)e*3+2];
  float ri = __builtin_amdgcn_rcpf(sqrtf(ex*ex + eyv*eyv + ezv*ezv) + 1e-12f);
  float X = ex*ri, Y = eyv*ri, Z = ezv*ri;
  const float s3 = 1.7320508075688772f;
  float Y1v[3] = {Y, Z, X};
  float Y2v[5] = {s3*X*Y, s3*Y*Z, 0.5f*(3.f*Z*Z - 1.f), s3*X*Z, 0.5f*s3*(X*X - Y*Y)};

  // ---- per-edge Y-contracted CG: B_p[a][c] = sum_b CG_p[a][b][c] * Y_{l2}[b]
  float B0 = cg[0];                               // p0 (0,0,0), Y0=1
  float B1[3], B2[5], B3[9], B4[3], B5[9], B6[15], B7[9], B8[15];
  #pragma unroll
  for (int c = 0; c < 3; ++c){ float s = 0.f;     // p1 (0,1,1)
    #pragma unroll
    for (int b = 0; b < 3; ++b) s += cg[1 + b*3 + c] * Y1v[b];
    B1[c] = s; }
  #pragma unroll
  for (int c = 0; c < 5; ++c){ float s = 0.f;     // p2 (0,2,2)
    #pragma unroll
    for (int b = 0; b < 5; ++b) s += cg[10 + b*5 + c] * Y2v[b];
    B2[c] = s; }
  #pragma unroll
  for (int i = 0; i < 9; ++i) B3[i] = cg[35 + i]; // p3 (1,0,1), Y0=1
  #pragma unroll
  for (int a = 0; a < 3; ++a){ float s = 0.f;     // p4 (1,1,0)
    #pragma unroll
    for (int b = 0; b < 3; ++b) s += cg[44 + a*3 + b] * Y1v[b];
    B4[a] = s; }
  #pragma unroll
  for (int a = 0; a < 3; ++a)                     // p5 (1,1,1)
    #pragma unroll
    for (int c = 0; c < 3; ++c){ float s = 0.f;
      #pragma unroll
      for (int b = 0; b < 3; ++b) s += cg[53 + (a*3 + b)*3 + c] * Y1v[b];
      B5[a*3 + c] = s; }
  #pragma unroll
  for (int a = 0; a < 3; ++a)                     // p6 (1,1,2)
    #pragma unroll
    for (int c = 0; c < 5; ++c){ float s = 0.f;
      #pragma unroll
      for (int b = 0; b < 3; ++b) s += cg[80 + (a*3 + b)*5 + c] * Y1v[b];
      B6[a*5 + c] = s; }
  #pragma unroll
  for (int a = 0; a < 3; ++a)                     // p7 (1,2,1)
    #pragma unroll
    for (int c = 0; c < 3; ++c){ float s = 0.f;
      #pragma unroll
      for (int b = 0; b < 5; ++b) s += cg[125 + (a*5 + b)*3 + c] * Y2v[b];
      B7[a*3 + c] = s; }
  #pragma unroll
  for (int a = 0; a < 3; ++a)                     // p8 (1,2,2)
    #pragma unroll
    for (int c = 0; c < 5; ++c){ float s = 0.f;
      #pragma unroll
      for (int b = 0; b < 5; ++b) s += cg[170 + (a*5 + b)*5 + c] * Y2v[b];
      B8[a*5 + c] = s; }

  int src = ei[2*e], dst = ei[2*e + 1];
  const float* xr = nf + (size_t)src * 128;
  float* orow = out + (size_t)dst * 288;

  // ---- channel loop: W2 GEMV slice + silu + tensor product + scatter ----
  for (int u = 0; u < 32; ++u){
    float wv[9];
    #pragma unroll
    for (int p = 0; p < 9; ++p) wv[p] = 0.f;
    #pragma unroll
    for (int k = 0; k < 64; ++k){
      float hk = h1[k];
      #pragma unroll
      for (int p = 0; p < 9; ++p) wv[p] += hk * W2[k*288 + p*32 + u];
    }
    #pragma unroll
    for (int p = 0; p < 9; ++p) wv[p] = silu_f(wv[p]);

    float x0 = xr[u];
    float xa = xr[32 + 3*u + 0], xb = xr[32 + 3*u + 1], xc = xr[32 + 3*u + 2];

    // l3 = 0 : paths 0,4
    float a0 = wv[0] * (B0 * x0)
             + wv[4] * (B4[0]*xa + B4[1]*xb + B4[2]*xc);
    // l3 = 1 : paths 1,3,5,7
    float a1[3];
    #pragma unroll
    for (int c = 0; c < 3; ++c)
      a1[c] = wv[1] * (B1[c] * x0)
            + wv[3] * (B3[c]*xa + B3[3+c]*xb + B3[6+c]*xc)
            + wv[5] * (B5[c]*xa + B5[3+c]*xb + B5[6+c]*xc)
            + wv[7] * (B7[c]*xa + B7[3+c]*xb + B7[6+c]*xc);
    // l3 = 2 : paths 2,6,8
    float a2[5];
    #pragma unroll
    for (int c = 0; c < 5; ++c)
      a2[c] = wv[2] * (B2[c] * x0)
            + wv[6] * (B6[c]*xa + B6[5+c]*xb + B6[10+c]*xc)
            + wv[8] * (B8[c]*xa + B8[5+c]*xb + B8[10+c]*xc);

    unsafeAtomicAdd(&orow[u], a0);
    #pragma unroll
    for (int c = 0; c < 3; ++c) unsafeAtomicAdd(&orow[32 + 3*u + c], a1[c]);
    #pragma unroll
    for (int c = 0; c < 5; ++c) unsafeAtomicAdd(&orow[128 + 5*u + c], a2[c]);
  }
}

extern "C" void kernel_launch(void* const* d_in, const int* in_sizes, int n_in,
                              void* d_out, int out_size, void* d_ws, size_t ws_size,
                              hipStream_t stream)
{
  const float* nf = (const float*)d_in[0];   // (20000,128)
  const float* ef = (const float*)d_in[1];   // (320000,16)
  const float* ev = (const float*)d_in[2];   // (320000,3)
  const int*   ei = (const int*)  d_in[3];   // (320000,2)
  const float* W0 = (const float*)d_in[4];   // (16,64)
  const float* W1 = (const float*)d_in[5];   // (64,64)
  const float* W2 = (const float*)d_in[6];   // (64,288)
  float* out = (float*)d_out;
  float* cg  = (float*)d_ws;                 // 245 floats of CG tables

  int E = in_sizes[3] / 2;

  hipMemsetAsync(d_out, 0, (size_t)out_size * sizeof(float), stream);
  cg_init_kernel<<<1, 16, 0, stream>>>(cg);
  tfn_edge_kernel<<<(E + TPB - 1) / TPB, TPB, 0, stream>>>(nf, ef, ev, ei, W0, W1, W2, cg, out, E);
}

// Round 2
// 6366.068 us; speedup vs baseline: 1.0351x; 1.0351x over previous
//
#include <hip/hip_runtime.h>
#include <math.h>

#define TPB 256

// ---------------------------------------------------------------------------
// ws layout (4-byte units):
//   cg     float[256]   @ 0
//   counts int[N]       @ 256
//   starts int[N+1]     @ 256+N
//   cursor int[N]       @ 257+2N (rounded)
//   perm   int[E]
//   msg    float[E*288] (16B aligned)
// ---------------------------------------------------------------------------

__device__ double dfact(int n){ double r = 1.0; for (int i = 2; i <= n; ++i) r *= (double)i; return r; }

__device__ void build_u(int l, double ur[5][5], double ui[5][5]){
  for (int i = 0; i < 5; ++i) for (int j = 0; j < 5; ++j){ ur[i][j] = 0.0; ui[i][j] = 0.0; }
  ur[l][l] = 1.0;
  double s = 1.0 / sqrt(2.0);
  for (int m = 1; m <= l; ++m){
    double sg = (m & 1) ? -1.0 : 1.0;
    ur[l + m][l + m] = sg * s;
    ur[l + m][l - m] = s;
    ui[l - m][l - m] = s;
    ui[l - m][l + m] = -sg * s;
  }
}

__global__ void cg_init_kernel(float* __restrict__ cg){
  int p = threadIdx.x;
  if (p >= 9) return;
  const int L1[9] = {0,0,0,1,1,1,1,1,1};
  const int L2[9] = {0,1,2,0,1,1,1,2,2};
  const int L3[9] = {0,1,2,1,0,1,2,1,2};
  const int OFF[9] = {0,1,10,35,44,53,80,125,170};
  int l1 = L1[p], l2 = L2[p], l3 = L3[p];
  int n1 = 2*l1+1, n2 = 2*l2+1, n3 = 2*l3+1;

  double Cc[5][5][5];
  for (int i = 0; i < 5; ++i) for (int j = 0; j < 5; ++j) for (int k = 0; k < 5; ++k) Cc[i][j][k] = 0.0;
  for (int m1 = -l1; m1 <= l1; ++m1) for (int m2 = -l2; m2 <= l2; ++m2){
    int m3 = m1 + m2;
    if (m3 < -l3 || m3 > l3) continue;
    double pref = sqrt((double)(2*l3+1) * dfact(l1+l2-l3) * dfact(l1-l2+l3) * dfact(-l1+l2+l3) / dfact(l1+l2+l3+1));
    pref *= sqrt(dfact(l3+m3)*dfact(l3-m3)*dfact(l1-m1)*dfact(l1+m1)*dfact(l2-m2)*dfact(l2+m2));
    double s = 0.0;
    for (int k = 0; k <= l1 + l2 - l3; ++k){
      int a0 = k, a1 = l1+l2-l3-k, a2 = l1-m1-k, a3 = l2+m2-k, a4 = l3-l2+m1+k, a5 = l3-l1-m2+k;
      if (a0 < 0 || a1 < 0 || a2 < 0 || a3 < 0 || a4 < 0 || a5 < 0) continue;
      double d = dfact(a0)*dfact(a1)*dfact(a2)*dfact(a3)*dfact(a4)*dfact(a5);
      s += ((k & 1) ? -1.0 : 1.0) / d;
    }
    Cc[m1+l1][m2+l2][m3+l3] = pref * s;
  }

  double U1r[5][5], U1i[5][5], U2r[5][5], U2i[5][5], U3r[5][5], U3i[5][5];
  build_u(l1, U1r, U1i); build_u(l2, U2r, U2i); build_u(l3, U3r, U3i);

  double Tre[5][5][5], Tim[5][5][5];
  double mre = 0.0, mim = 0.0;
  for (int a = 0; a < n1; ++a) for (int b = 0; b < n2; ++b) for (int c = 0; c < n3; ++c){
    double sr = 0.0, si = 0.0;
    for (int m = 0; m < n1; ++m) for (int n = 0; n < n2; ++n) for (int o = 0; o < n3; ++o){
      double cc = Cc[m][n][o];
      if (cc == 0.0) continue;
      double xre = U1r[a][m], xim = U1i[a][m];
      double yre = U2r[b][n], yim = U2i[b][n];
      double zr = xre*yre - xim*yim, zi = xre*yim + xim*yre;
      double wr = U3r[c][o], wi = -U3i[c][o];
      double pr = zr*wr - zi*wi, pi = zr*wi + zi*wr;
      sr += pr * cc; si += pi * cc;
    }
    Tre[a][b][c] = sr; Tim[a][b][c] = si;
    if (fabs(sr) > mre) mre = fabs(sr);
    if (fabs(si) > mim) mim = fabs(si);
  }
  int use_re = (mre >= mim);
  for (int a = 0; a < n1; ++a) for (int b = 0; b < n2; ++b) for (int c = 0; c < n3; ++c)
    cg[OFF[p] + (a*n2 + b)*n3 + c] = (float)(use_re ? Tre[a][b][c] : Tim[a][b][c]);
}

// ---------------- CSR build ----------------

__global__ void hist_kernel(const int* __restrict__ ei, int* __restrict__ counts, int E){
  int e = blockIdx.x * TPB + threadIdx.x;
  if (e < E) atomicAdd(&counts[ei[2*e + 1]], 1);
}

__global__ void scan_kernel(const int* __restrict__ counts, int* __restrict__ starts,
                            int* __restrict__ cursor, int N){
  __shared__ int part[1024];
  int t = threadIdx.x;
  int T = (N + 1023) >> 10;
  int base = t * T;
  int s = 0;
  for (int i = 0; i < T; ++i){ int idx = base + i; if (idx < N) s += counts[idx]; }
  part[t] = s; __syncthreads();
  for (int off = 1; off < 1024; off <<= 1){
    int v = (t >= off) ? part[t - off] : 0;
    __syncthreads();
    part[t] += v;
    __syncthreads();
  }
  int excl = (t == 0) ? 0 : part[t - 1];
  for (int i = 0; i < T; ++i){
    int idx = base + i;
    if (idx < N){ starts[idx] = excl; cursor[idx] = excl; excl += counts[idx]; }
  }
  if (t == 1023) starts[N] = part[1023];
}

__global__ void perm_kernel(const int* __restrict__ ei, int* __restrict__ cursor,
                            int* __restrict__ perm, int E){
  int e = blockIdx.x * TPB + threadIdx.x;
  if (e < E){
    int pos = atomicAdd(&cursor[ei[2*e + 1]], 1);
    perm[pos] = e;
  }
}

// ---------------- per-edge compute ----------------

__device__ __forceinline__ float silu_f(float x){
  float t = __expf(-x);
  return x * __builtin_amdgcn_rcpf(1.0f + t);
}

// Computes the full per-edge message into msg_row[0..287] (register-light caller).
template<bool SCATTER>
__device__ __forceinline__ void edge_body(
    int e, const float* __restrict__ nf, const float* __restrict__ ef,
    const float* __restrict__ ev, const int* __restrict__ ei,
    const float* __restrict__ W0, const float* __restrict__ W1,
    const float* __restrict__ W2, const float* __restrict__ cg,
    float* __restrict__ orow)
{
  float f0[16];
  #pragma unroll
  for (int q = 0; q < 16; ++q) f0[q] = ef[(size_t)e*16 + q];

  float h1[64];
  #pragma unroll
  for (int j = 0; j < 64; ++j) h1[j] = 0.f;
  for (int k = 0; k < 64; ++k){
    float a = 0.f;
    #pragma unroll
    for (int q = 0; q < 16; ++q) a += f0[q] * W0[q*64 + k];
    float g = silu_f(a);
    #pragma unroll
    for (int j = 0; j < 64; ++j) h1[j] += g * W1[k*64 + j];
  }
  #pragma unroll
  for (int j = 0; j < 64; ++j) h1[j] = silu_f(h1[j]);

  float ex = ev[(size_t)e*3+0], eyv = ev[(size_t)e*3+1], ezv = ev[(size_t)e*3+2];
  float ri = __builtin_amdgcn_rcpf(sqrtf(ex*ex + eyv*eyv + ezv*ezv) + 1e-12f);
  float X = ex*ri, Y = eyv*ri, Z = ezv*ri;
  const float s3 = 1.7320508075688772f;
  float Y1v[3] = {Y, Z, X};
  float Y2v[5] = {s3*X*Y, s3*Y*Z, 0.5f*(3.f*Z*Z - 1.f), s3*X*Z, 0.5f*s3*(X*X - Y*Y)};

  float B0 = cg[0];
  float B1[3], B2[5], B3[9], B4[3], B5[9], B6[15], B7[9], B8[15];
  #pragma unroll
  for (int c = 0; c < 3; ++c){ float s = 0.f;
    #pragma unroll
    for (int b = 0; b < 3; ++b) s += cg[1 + b*3 + c] * Y1v[b];
    B1[c] = s; }
  #pragma unroll
  for (int c = 0; c < 5; ++c){ float s = 0.f;
    #pragma unroll
    for (int b = 0; b < 5; ++b) s += cg[10 + b*5 + c] * Y2v[b];
    B2[c] = s; }
  #pragma unroll
  for (int i = 0; i < 9; ++i) B3[i] = cg[35 + i];
  #pragma unroll
  for (int a = 0; a < 3; ++a){ float s = 0.f;
    #pragma unroll
    for (int b = 0; b < 3; ++b) s += cg[44 + a*3 + b] * Y1v[b];
    B4[a] = s; }
  #pragma unroll
  for (int a = 0; a < 3; ++a)
    #pragma unroll
    for (int c = 0; c < 3; ++c){ float s = 0.f;
      #pragma unroll
      for (int b = 0; b < 3; ++b) s += cg[53 + (a*3 + b)*3 + c] * Y1v[b];
      B5[a*3 + c] = s; }
  #pragma unroll
  for (int a = 0; a < 3; ++a)
    #pragma unroll
    for (int c = 0; c < 5; ++c){ float s = 0.f;
      #pragma unroll
      for (int b = 0; b < 3; ++b) s += cg[80 + (a*3 + b)*5 + c] * Y1v[b];
      B6[a*5 + c] = s; }
  #pragma unroll
  for (int a = 0; a < 3; ++a)
    #pragma unroll
    for (int c = 0; c < 3; ++c){ float s = 0.f;
      #pragma unroll
      for (int b = 0; b < 5; ++b) s += cg[125 + (a*5 + b)*3 + c] * Y2v[b];
      B7[a*3 + c] = s; }
  #pragma unroll
  for (int a = 0; a < 3; ++a)
    #pragma unroll
    for (int c = 0; c < 5; ++c){ float s = 0.f;
      #pragma unroll
      for (int b = 0; b < 5; ++b) s += cg[170 + (a*5 + b)*5 + c] * Y2v[b];
      B8[a*5 + c] = s; }

  int src = ei[2*e];
  const float* xr = nf + (size_t)src * 128;

  for (int u = 0; u < 32; ++u){
    float wv[9];
    #pragma unroll
    for (int p = 0; p < 9; ++p) wv[p] = 0.f;
    #pragma unroll
    for (int k = 0; k < 64; ++k){
      float hk = h1[k];
      #pragma unroll
      for (int p = 0; p < 9; ++p) wv[p] += hk * W2[k*288 + p*32 + u];
    }
    #pragma unroll
    for (int p = 0; p < 9; ++p) wv[p] = silu_f(wv[p]);

    float x0 = xr[u];
    float xa = xr[32 + 3*u + 0], xb = xr[32 + 3*u + 1], xc = xr[32 + 3*u + 2];

    float a0 = wv[0] * (B0 * x0)
             + wv[4] * (B4[0]*xa + B4[1]*xb + B4[2]*xc);
    float a1[3];
    #pragma unroll
    for (int c = 0; c < 3; ++c)
      a1[c] = wv[1] * (B1[c] * x0)
            + wv[3] * (B3[c]*xa + B3[3+c]*xb + B3[6+c]*xc)
            + wv[5] * (B5[c]*xa + B5[3+c]*xb + B5[6+c]*xc)
            + wv[7] * (B7[c]*xa + B7[3+c]*xb + B7[6+c]*xc);
    float a2[5];
    #pragma unroll
    for (int c = 0; c < 5; ++c)
      a2[c] = wv[2] * (B2[c] * x0)
            + wv[6] * (B6[c]*xa + B6[5+c]*xb + B6[10+c]*xc)
            + wv[8] * (B8[c]*xa + B8[5+c]*xb + B8[10+c]*xc);

    if (SCATTER){
      unsafeAtomicAdd(&orow[u], a0);
      #pragma unroll
      for (int c = 0; c < 3; ++c) unsafeAtomicAdd(&orow[32 + 3*u + c], a1[c]);
      #pragma unroll
      for (int c = 0; c < 5; ++c) unsafeAtomicAdd(&orow[128 + 5*u + c], a2[c]);
    } else {
      orow[u] = a0;
      #pragma unroll
      for (int c = 0; c < 3; ++c) orow[32 + 3*u + c] = a1[c];
      #pragma unroll
      for (int c = 0; c < 5; ++c) orow[128 + 5*u + c] = a2[c];
    }
  }
}

__global__ void __launch_bounds__(TPB, 2) tfn_compute_kernel(
    const float* __restrict__ nf, const float* __restrict__ ef,
    const float* __restrict__ ev, const int* __restrict__ ei,
    const float* __restrict__ W0, const float* __restrict__ W1,
    const float* __restrict__ W2, const float* __restrict__ cg,
    const int* __restrict__ perm, float* __restrict__ msg, int E)
{
  int t = blockIdx.x * TPB + threadIdx.x;
  if (t >= E) return;
  int e = perm[t];
  edge_body<false>(e, nf, ef, ev, ei, W0, W1, W2, cg, msg + (size_t)t * 288);
}

// fallback (atomic) path, only if ws too small
__global__ void __launch_bounds__(TPB, 2) tfn_atomic_kernel(
    const float* __restrict__ nf, const float* __restrict__ ef,
    const float* __restrict__ ev, const int* __restrict__ ei,
    const float* __restrict__ W0, const float* __restrict__ W1,
    const float* __restrict__ W2, const float* __restrict__ cg,
    float* __restrict__ out, int E)
{
  int e = blockIdx.x * TPB + threadIdx.x;
  if (e >= E) return;
  int dst = ei[2*e + 1];
  edge_body<true>(e, nf, ef, ev, ei, W0, W1, W2, cg, out + (size_t)dst * 288);
}

// ---------------- gather ----------------

__global__ void gather_kernel(const float* __restrict__ msg, const int* __restrict__ starts,
                              float* __restrict__ out, int N)
{
  int n = blockIdx.x;
  int c = threadIdx.x;            // 0..127
  int s = starts[n], t = starts[n + 1];
  float a0 = 0.f, a1 = 0.f, a2 = 0.f;
  for (int i = s; i < t; ++i){
    const float* row = msg + (size_t)i * 288;
    a0 += row[c];
    a1 += row[c + 128];
    if (c < 32) a2 += row[c + 256];
  }
  float* o = out + (size_t)n * 288;
  o[c] = a0;
  o[c + 128] = a1;
  if (c < 32) o[c + 256] = a2;
}

extern "C" void kernel_launch(void* const* d_in, const int* in_sizes, int n_in,
                              void* d_out, int out_size, void* d_ws, size_t ws_size,
                              hipStream_t stream)
{
  const float* nf = (const float*)d_in[0];
  const float* ef = (const float*)d_in[1];
  const float* ev = (const float*)d_in[2];
  const int*   ei = (const int*)  d_in[3];
  const float* W0 = (const float*)d_in[4];
  const float* W1 = (const float*)d_in[5];
  const float* W2 = (const float*)d_in[6];
  float* out = (float*)d_out;

  int E = in_sizes[3] / 2;
  int N = in_sizes[0] / 128;

  // ws layout (units of 4 bytes)
  float* cg     = (float*)d_ws;                       // 256
  int*   counts = (int*)d_ws + 256;                   // N
  int*   starts = counts + N;                         // N+1
  int*   cursor = starts + N + 1;                     // N
  int*   perm   = cursor + N;                         // E
  size_t msg_off = (size_t)(256 + 3*N + 1 + E);
  msg_off = (msg_off + 3) & ~(size_t)3;               // 16B align
  float* msg    = (float*)d_ws + msg_off;
  size_t need_bytes = (msg_off + (size_t)E * 288) * 4;

  cg_init_kernel<<<1, 16, 0, stream>>>(cg);

  if (ws_size >= need_bytes){
    hipMemsetAsync(counts, 0, (size_t)N * sizeof(int), stream);
    hist_kernel<<<(E + TPB - 1) / TPB, TPB, 0, stream>>>(ei, counts, E);
    scan_kernel<<<1, 1024, 0, stream>>>(counts, starts, cursor, N);
    perm_kernel<<<(E + TPB - 1) / TPB, TPB, 0, stream>>>(ei, cursor, perm, E);
    tfn_compute_kernel<<<(E + TPB - 1) / TPB, TPB, 0, stream>>>(nf, ef, ev, ei, W0, W1, W2, cg, perm, msg, E);
    gather_kernel<<<N, 128, 0, stream>>>(msg, starts, out, N);
  } else {
    hipMemsetAsync(d_out, 0, (size_t)out_size * sizeof(float), stream);
    tfn_atomic_kernel<<<(E + TPB - 1) / TPB, TPB, 0, stream>>>(nf, ef, ev, ei, W0, W1, W2, cg, out, E);
  }
}

// Round 3
// 1978.304 us; speedup vs baseline: 3.3308x; 3.2179x over previous
//
#include <hip/hip_runtime.h>
#include <math.h>

#define TPB 256

// ---------------------------------------------------------------------------
// ws layout (4-byte units):
//   cg     float[256]   @ 0
//   counts int[N]       @ 256
//   starts int[N+1]     @ 256+N
//   cursor int[N]       @ 257+2N
//   perm   int[E]
// total ~1.5 MB. Edges processed in dst-sorted order (perm); per-wave
// segmented shuffle-reduction so only segment tails issue global atomics.
// ---------------------------------------------------------------------------

__device__ double dfact(int n){ double r = 1.0; for (int i = 2; i <= n; ++i) r *= (double)i; return r; }

__device__ void build_u(int l, double ur[5][5], double ui[5][5]){
  for (int i = 0; i < 5; ++i) for (int j = 0; j < 5; ++j){ ur[i][j] = 0.0; ui[i][j] = 0.0; }
  ur[l][l] = 1.0;
  double s = 1.0 / sqrt(2.0);
  for (int m = 1; m <= l; ++m){
    double sg = (m & 1) ? -1.0 : 1.0;
    ur[l + m][l + m] = sg * s;
    ur[l + m][l - m] = s;
    ui[l - m][l - m] = s;
    ui[l - m][l + m] = -sg * s;
  }
}

__global__ void cg_init_kernel(float* __restrict__ cg){
  int p = threadIdx.x;
  if (p >= 9) return;
  const int L1[9] = {0,0,0,1,1,1,1,1,1};
  const int L2[9] = {0,1,2,0,1,1,1,2,2};
  const int L3[9] = {0,1,2,1,0,1,2,1,2};
  const int OFF[9] = {0,1,10,35,44,53,80,125,170};
  int l1 = L1[p], l2 = L2[p], l3 = L3[p];
  int n1 = 2*l1+1, n2 = 2*l2+1, n3 = 2*l3+1;

  double Cc[5][5][5];
  for (int i = 0; i < 5; ++i) for (int j = 0; j < 5; ++j) for (int k = 0; k < 5; ++k) Cc[i][j][k] = 0.0;
  for (int m1 = -l1; m1 <= l1; ++m1) for (int m2 = -l2; m2 <= l2; ++m2){
    int m3 = m1 + m2;
    if (m3 < -l3 || m3 > l3) continue;
    double pref = sqrt((double)(2*l3+1) * dfact(l1+l2-l3) * dfact(l1-l2+l3) * dfact(-l1+l2+l3) / dfact(l1+l2+l3+1));
    pref *= sqrt(dfact(l3+m3)*dfact(l3-m3)*dfact(l1-m1)*dfact(l1+m1)*dfact(l2-m2)*dfact(l2+m2));
    double s = 0.0;
    for (int k = 0; k <= l1 + l2 - l3; ++k){
      int a0 = k, a1 = l1+l2-l3-k, a2 = l1-m1-k, a3 = l2+m2-k, a4 = l3-l2+m1+k, a5 = l3-l1-m2+k;
      if (a0 < 0 || a1 < 0 || a2 < 0 || a3 < 0 || a4 < 0 || a5 < 0) continue;
      double d = dfact(a0)*dfact(a1)*dfact(a2)*dfact(a3)*dfact(a4)*dfact(a5);
      s += ((k & 1) ? -1.0 : 1.0) / d;
    }
    Cc[m1+l1][m2+l2][m3+l3] = pref * s;
  }

  double U1r[5][5], U1i[5][5], U2r[5][5], U2i[5][5], U3r[5][5], U3i[5][5];
  build_u(l1, U1r, U1i); build_u(l2, U2r, U2i); build_u(l3, U3r, U3i);

  double Tre[5][5][5], Tim[5][5][5];
  double mre = 0.0, mim = 0.0;
  for (int a = 0; a < n1; ++a) for (int b = 0; b < n2; ++b) for (int c = 0; c < n3; ++c){
    double sr = 0.0, si = 0.0;
    for (int m = 0; m < n1; ++m) for (int n = 0; n < n2; ++n) for (int o = 0; o < n3; ++o){
      double cc = Cc[m][n][o];
      if (cc == 0.0) continue;
      double xre = U1r[a][m], xim = U1i[a][m];
      double yre = U2r[b][n], yim = U2i[b][n];
      double zr = xre*yre - xim*yim, zi = xre*yim + xim*yre;
      double wr = U3r[c][o], wi = -U3i[c][o];
      double pr = zr*wr - zi*wi, pi = zr*wi + zi*wr;
      sr += pr * cc; si += pi * cc;
    }
    Tre[a][b][c] = sr; Tim[a][b][c] = si;
    if (fabs(sr) > mre) mre = fabs(sr);
    if (fabs(si) > mim) mim = fabs(si);
  }
  int use_re = (mre >= mim);
  for (int a = 0; a < n1; ++a) for (int b = 0; b < n2; ++b) for (int c = 0; c < n3; ++c)
    cg[OFF[p] + (a*n2 + b)*n3 + c] = (float)(use_re ? Tre[a][b][c] : Tim[a][b][c]);
}

// ---------------- CSR build ----------------

__global__ void hist_kernel(const int* __restrict__ ei, int* __restrict__ counts, int E){
  int e = blockIdx.x * TPB + threadIdx.x;
  if (e < E) atomicAdd(&counts[ei[2*e + 1]], 1);
}

__global__ void scan_kernel(const int* __restrict__ counts, int* __restrict__ starts,
                            int* __restrict__ cursor, int N){
  __shared__ int part[1024];
  int t = threadIdx.x;
  int T = (N + 1023) >> 10;
  int base = t * T;
  int s = 0;
  for (int i = 0; i < T; ++i){ int idx = base + i; if (idx < N) s += counts[idx]; }
  part[t] = s; __syncthreads();
  for (int off = 1; off < 1024; off <<= 1){
    int v = (t >= off) ? part[t - off] : 0;
    __syncthreads();
    part[t] += v;
    __syncthreads();
  }
  int excl = (t == 0) ? 0 : part[t - 1];
  for (int i = 0; i < T; ++i){
    int idx = base + i;
    if (idx < N){ starts[idx] = excl; cursor[idx] = excl; excl += counts[idx]; }
  }
  if (t == 1023) starts[N] = part[1023];
}

__global__ void perm_kernel(const int* __restrict__ ei, int* __restrict__ cursor,
                            int* __restrict__ perm, int E){
  int e = blockIdx.x * TPB + threadIdx.x;
  if (e < E){
    int pos = atomicAdd(&cursor[ei[2*e + 1]], 1);
    perm[pos] = e;
  }
}

// ---------------- per-edge compute ----------------

__device__ __forceinline__ float silu_f(float x){
  float t = __expf(-x);
  return x * __builtin_amdgcn_rcpf(1.0f + t);
}

// Per-wave segmented inclusive scan (dst non-decreasing within wave):
// after SEGSUM, each segment's last lane holds the segment total.
#define SEGSUM(v) { float _o; \
  _o = __shfl_up(v, 1);  v += samef[0]*_o; \
  _o = __shfl_up(v, 2);  v += samef[1]*_o; \
  _o = __shfl_up(v, 4);  v += samef[2]*_o; \
  _o = __shfl_up(v, 8);  v += samef[3]*_o; \
  _o = __shfl_up(v, 16); v += samef[4]*_o; \
  _o = __shfl_up(v, 32); v += samef[5]*_o; }

__global__ void __launch_bounds__(TPB, 2) tfn_sorted_kernel(
    const float* __restrict__ nf, const float* __restrict__ ef,
    const float* __restrict__ ev, const int* __restrict__ ei,
    const float* __restrict__ W0, const float* __restrict__ W1,
    const float* __restrict__ W2, const float* __restrict__ cg,
    const int* __restrict__ perm, float* __restrict__ out, int E)
{
  int t = blockIdx.x * TPB + threadIdx.x;
  bool valid = (t < E);
  int e = perm[valid ? t : (E - 1)];
  int d = valid ? ei[2*e + 1] : -1;   // sentinel only in the top lanes of last wave
  int lane = threadIdx.x & 63;

  // segment predicates (uniform over the whole u-loop)
  float samef[6];
  #pragma unroll
  for (int s = 0; s < 6; ++s){
    int off = 1 << s;
    int od = __shfl_up(d, off);
    samef[s] = (lane >= off && od == d) ? 1.0f : 0.0f;
  }
  int nd = __shfl_down(d, 1);
  bool tail = valid && ((lane == 63) || (nd != d));

  // ---- edge features ----
  float f0[16];
  #pragma unroll
  for (int q = 0; q < 16; ++q) f0[q] = ef[(size_t)e*16 + q];

  // ---- MLP layers 0+1 fused ----
  float h1[64];
  #pragma unroll
  for (int j = 0; j < 64; ++j) h1[j] = 0.f;
  for (int k = 0; k < 64; ++k){
    float a = 0.f;
    #pragma unroll
    for (int q = 0; q < 16; ++q) a += f0[q] * W0[q*64 + k];
    float g = silu_f(a);
    #pragma unroll
    for (int j = 0; j < 64; ++j) h1[j] += g * W1[k*64 + j];
  }
  #pragma unroll
  for (int j = 0; j < 64; ++j) h1[j] = silu_f(h1[j]);

  // ---- spherical harmonics ----
  float ex = ev[(size_t)e*3+0], eyv = ev[(size_t)e*3+1], ezv = ev[(size_t)e*3+2];
  float ri = __builtin_amdgcn_rcpf(sqrtf(ex*ex + eyv*eyv + ezv*ezv) + 1e-12f);
  float X = ex*ri, Y = eyv*ri, Z = ezv*ri;
  const float s3 = 1.7320508075688772f;
  float Y1v[3] = {Y, Z, X};
  float Y2v[5] = {s3*X*Y, s3*Y*Z, 0.5f*(3.f*Z*Z - 1.f), s3*X*Z, 0.5f*s3*(X*X - Y*Y)};

  // ---- Y-contracted CG ----
  float B0 = cg[0];
  float B1[3], B2[5], B3[9], B4[3], B5[9], B6[15], B7[9], B8[15];
  #pragma unroll
  for (int c = 0; c < 3; ++c){ float s = 0.f;
    #pragma unroll
    for (int b = 0; b < 3; ++b) s += cg[1 + b*3 + c] * Y1v[b];
    B1[c] = s; }
  #pragma unroll
  for (int c = 0; c < 5; ++c){ float s = 0.f;
    #pragma unroll
    for (int b = 0; b < 5; ++b) s += cg[10 + b*5 + c] * Y2v[b];
    B2[c] = s; }
  #pragma unroll
  for (int i = 0; i < 9; ++i) B3[i] = cg[35 + i];
  #pragma unroll
  for (int a = 0; a < 3; ++a){ float s = 0.f;
    #pragma unroll
    for (int b = 0; b < 3; ++b) s += cg[44 + a*3 + b] * Y1v[b];
    B4[a] = s; }
  #pragma unroll
  for (int a = 0; a < 3; ++a)
    #pragma unroll
    for (int c = 0; c < 3; ++c){ float s = 0.f;
      #pragma unroll
      for (int b = 0; b < 3; ++b) s += cg[53 + (a*3 + b)*3 + c] * Y1v[b];
      B5[a*3 + c] = s; }
  #pragma unroll
  for (int a = 0; a < 3; ++a)
    #pragma unroll
    for (int c = 0; c < 5; ++c){ float s = 0.f;
      #pragma unroll
      for (int b = 0; b < 3; ++b) s += cg[80 + (a*3 + b)*5 + c] * Y1v[b];
      B6[a*5 + c] = s; }
  #pragma unroll
  for (int a = 0; a < 3; ++a)
    #pragma unroll
    for (int c = 0; c < 3; ++c){ float s = 0.f;
      #pragma unroll
      for (int b = 0; b < 5; ++b) s += cg[125 + (a*5 + b)*3 + c] * Y2v[b];
      B7[a*3 + c] = s; }
  #pragma unroll
  for (int a = 0; a < 3; ++a)
    #pragma unroll
    for (int c = 0; c < 5; ++c){ float s = 0.f;
      #pragma unroll
      for (int b = 0; b < 5; ++b) s += cg[170 + (a*5 + b)*5 + c] * Y2v[b];
      B8[a*5 + c] = s; }

  int src = ei[2*e];
  const float* xr = nf + (size_t)src * 128;
  float* orow = out + (size_t)(d < 0 ? 0 : d) * 288;

  for (int u = 0; u < 32; ++u){
    float wv[9];
    #pragma unroll
    for (int p = 0; p < 9; ++p) wv[p] = 0.f;
    #pragma unroll
    for (int k = 0; k < 64; ++k){
      float hk = h1[k];
      #pragma unroll
      for (int p = 0; p < 9; ++p) wv[p] += hk * W2[k*288 + p*32 + u];
    }
    #pragma unroll
    for (int p = 0; p < 9; ++p) wv[p] = silu_f(wv[p]);

    float x0 = xr[u];
    float xa = xr[32 + 3*u + 0], xb = xr[32 + 3*u + 1], xc = xr[32 + 3*u + 2];

    float a0 = wv[0] * (B0 * x0)
             + wv[4] * (B4[0]*xa + B4[1]*xb + B4[2]*xc);
    float a1[3];
    #pragma unroll
    for (int c = 0; c < 3; ++c)
      a1[c] = wv[1] * (B1[c] * x0)
            + wv[3] * (B3[c]*xa + B3[3+c]*xb + B3[6+c]*xc)
            + wv[5] * (B5[c]*xa + B5[3+c]*xb + B5[6+c]*xc)
            + wv[7] * (B7[c]*xa + B7[3+c]*xb + B7[6+c]*xc);
    float a2[5];
    #pragma unroll
    for (int c = 0; c < 5; ++c)
      a2[c] = wv[2] * (B2[c] * x0)
            + wv[6] * (B6[c]*xa + B6[5+c]*xb + B6[10+c]*xc)
            + wv[8] * (B8[c]*xa + B8[5+c]*xb + B8[10+c]*xc);

    // wave-level segmented reduction (uniform control flow: all lanes shuffle)
    SEGSUM(a0);
    #pragma unroll
    for (int c = 0; c < 3; ++c) SEGSUM(a1[c]);
    #pragma unroll
    for (int c = 0; c < 5; ++c) SEGSUM(a2[c]);

    if (tail){
      unsafeAtomicAdd(&orow[u], a0);
      #pragma unroll
      for (int c = 0; c < 3; ++c) unsafeAtomicAdd(&orow[32 + 3*u + c], a1[c]);
      #pragma unroll
      for (int c = 0; c < 5; ++c) unsafeAtomicAdd(&orow[128 + 5*u + c], a2[c]);
    }
  }
}

// fallback (atomic per edge) if ws too small for CSR arrays
__global__ void __launch_bounds__(TPB, 2) tfn_atomic_kernel(
    const float* __restrict__ nf, const float* __restrict__ ef,
    const float* __restrict__ ev, const int* __restrict__ ei,
    const float* __restrict__ W0, const float* __restrict__ W1,
    const float* __restrict__ W2, const float* __restrict__ cg,
    float* __restrict__ out, int E)
{
  int e = blockIdx.x * TPB + threadIdx.x;
  if (e >= E) return;

  float f0[16];
  #pragma unroll
  for (int q = 0; q < 16; ++q) f0[q] = ef[(size_t)e*16 + q];
  float h1[64];
  #pragma unroll
  for (int j = 0; j < 64; ++j) h1[j] = 0.f;
  for (int k = 0; k < 64; ++k){
    float a = 0.f;
    #pragma unroll
    for (int q = 0; q < 16; ++q) a += f0[q] * W0[q*64 + k];
    float g = silu_f(a);
    #pragma unroll
    for (int j = 0; j < 64; ++j) h1[j] += g * W1[k*64 + j];
  }
  #pragma unroll
  for (int j = 0; j < 64; ++j) h1[j] = silu_f(h1[j]);

  float ex = ev[(size_t)e*3+0], eyv = ev[(size_t)e*3+1], ezv = ev[(size_t)e*3+2];
  float ri = __builtin_amdgcn_rcpf(sqrtf(ex*ex + eyv*eyv + ezv*ezv) + 1e-12f);
  float X = ex*ri, Y = eyv*ri, Z = ezv*ri;
  const float s3 = 1.7320508075688772f;
  float Y1v[3] = {Y, Z, X};
  float Y2v[5] = {s3*X*Y, s3*Y*Z, 0.5f*(3.f*Z*Z - 1.f), s3*X*Z, 0.5f*s3*(X*X - Y*Y)};

  float B0 = cg[0];
  float B1[3], B2[5], B3[9], B4[3], B5[9], B6[15], B7[9], B8[15];
  #pragma unroll
  for (int c = 0; c < 3; ++c){ float s = 0.f;
    #pragma unroll
    for (int b = 0; b < 3; ++b) s += cg[1 + b*3 + c] * Y1v[b];
    B1[c] = s; }
  #pragma unroll
  for (int c = 0; c < 5; ++c){ float s = 0.f;
    #pragma unroll
    for (int b = 0; b < 5; ++b) s += cg[10 + b*5 + c] * Y2v[b];
    B2[c] = s; }
  #pragma unroll
  for (int i = 0; i < 9; ++i) B3[i] = cg[35 + i];
  #pragma unroll
  for (int a = 0; a < 3; ++a){ float s = 0.f;
    #pragma unroll
    for (int b = 0; b < 3; ++b) s += cg[44 + a*3 + b] * Y1v[b];
    B4[a] = s; }
  #pragma unroll
  for (int a = 0; a < 3; ++a)
    #pragma unroll
    for (int c = 0; c < 3; ++c){ float s = 0.f;
      #pragma unroll
      for (int b = 0; b < 3; ++b) s += cg[53 + (a*3 + b)*3 + c] * Y1v[b];
      B5[a*3 + c] = s; }
  #pragma unroll
  for (int a = 0; a < 3; ++a)
    #pragma unroll
    for (int c = 0; c < 5; ++c){ float s = 0.f;
      #pragma unroll
      for (int b = 0; b < 3; ++b) s += cg[80 + (a*3 + b)*5 + c] * Y1v[b];
      B6[a*5 + c] = s; }
  #pragma unroll
  for (int a = 0; a < 3; ++a)
    #pragma unroll
    for (int c = 0; c < 3; ++c){ float s = 0.f;
      #pragma unroll
      for (int b = 0; b < 5; ++b) s += cg[125 + (a*5 + b)*3 + c] * Y2v[b];
      B7[a*3 + c] = s; }
  #pragma unroll
  for (int a = 0; a < 3; ++a)
    #pragma unroll
    for (int c = 0; c < 5; ++c){ float s = 0.f;
      #pragma unroll
      for (int b = 0; b < 5; ++b) s += cg[170 + (a*5 + b)*5 + c] * Y2v[b];
      B8[a*5 + c] = s; }

  int src = ei[2*e], dst = ei[2*e + 1];
  const float* xr = nf + (size_t)src * 128;
  float* orow = out + (size_t)dst * 288;

  for (int u = 0; u < 32; ++u){
    float wv[9];
    #pragma unroll
    for (int p = 0; p < 9; ++p) wv[p] = 0.f;
    #pragma unroll
    for (int k = 0; k < 64; ++k){
      float hk = h1[k];
      #pragma unroll
      for (int p = 0; p < 9; ++p) wv[p] += hk * W2[k*288 + p*32 + u];
    }
    #pragma unroll
    for (int p = 0; p < 9; ++p) wv[p] = silu_f(wv[p]);

    float x0 = xr[u];
    float xa = xr[32 + 3*u + 0], xb = xr[32 + 3*u + 1], xc = xr[32 + 3*u + 2];

    float a0 = wv[0] * (B0 * x0)
             + wv[4] * (B4[0]*xa + B4[1]*xb + B4[2]*xc);
    float a1[3];
    #pragma unroll
    for (int c = 0; c < 3; ++c)
      a1[c] = wv[1] * (B1[c] * x0)
            + wv[3] * (B3[c]*xa + B3[3+c]*xb + B3[6+c]*xc)
            + wv[5] * (B5[c]*xa + B5[3+c]*xb + B5[6+c]*xc)
            + wv[7] * (B7[c]*xa + B7[3+c]*xb + B7[6+c]*xc);
    float a2[5];
    #pragma unroll
    for (int c = 0; c < 5; ++c)
      a2[c] = wv[2] * (B2[c] * x0)
            + wv[6] * (B6[c]*xa + B6[5+c]*xb + B6[10+c]*xc)
            + wv[8] * (B8[c]*xa + B8[5+c]*xb + B8[10+c]*xc);

    unsafeAtomicAdd(&orow[u], a0);
    #pragma unroll
    for (int c = 0; c < 3; ++c) unsafeAtomicAdd(&orow[32 + 3*u + c], a1[c]);
    #pragma unroll
    for (int c = 0; c < 5; ++c) unsafeAtomicAdd(&orow[128 + 5*u + c], a2[c]);
  }
}

extern "C" void kernel_launch(void* const* d_in, const int* in_sizes, int n_in,
                              void* d_out, int out_size, void* d_ws, size_t ws_size,
                              hipStream_t stream)
{
  const float* nf = (const float*)d_in[0];
  const float* ef = (const float*)d_in[1];
  const float* ev = (const float*)d_in[2];
  const int*   ei = (const int*)  d_in[3];
  const float* W0 = (const float*)d_in[4];
  const float* W1 = (const float*)d_in[5];
  const float* W2 = (const float*)d_in[6];
  float* out = (float*)d_out;

  int E = in_sizes[3] / 2;
  int N = in_sizes[0] / 128;

  float* cg     = (float*)d_ws;                       // 256
  int*   counts = (int*)d_ws + 256;                   // N
  int*   starts = counts + N;                         // N+1
  int*   cursor = starts + N + 1;                     // N
  int*   perm   = cursor + N;                         // E
  size_t need_bytes = (size_t)(256 + 3*N + 1 + E) * 4;

  cg_init_kernel<<<1, 16, 0, stream>>>(cg);
  hipMemsetAsync(d_out, 0, (size_t)out_size * sizeof(float), stream);

  if (ws_size >= need_bytes){
    hipMemsetAsync(counts, 0, (size_t)N * sizeof(int), stream);
    hist_kernel<<<(E + TPB - 1) / TPB, TPB, 0, stream>>>(ei, counts, E);
    scan_kernel<<<1, 1024, 0, stream>>>(counts, starts, cursor, N);
    perm_kernel<<<(E + TPB - 1) / TPB, TPB, 0, stream>>>(ei, cursor, perm, E);
    tfn_sorted_kernel<<<(E + TPB - 1) / TPB, TPB, 0, stream>>>(nf, ef, ev, ei, W0, W1, W2, cg, perm, out, E);
  } else {
    tfn_atomic_kernel<<<(E + TPB - 1) / TPB, TPB, 0, stream>>>(nf, ef, ev, ei, W0, W1, W2, cg, out, E);
  }
}